// Round 4
// baseline (57.303 us; speedup 1.0000x reference)
//
#include <hip/hip_runtime.h>

#define BB 32
#define CC 16
#define HH 256
#define WW 256
#define HWSZ (HH * WW)

#define TW 64                  // tile width (x)
#define TH 16                  // tile height (y)
#define XT (WW / TW)           // 4 x-tiles
#define YT (HH / TH)           // 16 y-tiles
#define NBLK (BB * XT * YT)    // 2048 blocks
#define NXCD 8

#define SROWS 56               // staged row capacity
#define SCOLS 96               // staged col capacity (multiple of 4)
#define SF4 (SCOLS / 4)        // 24 float4 per staged row

typedef float f2 __attribute__((ext_vector_type(2)));
typedef float f4 __attribute__((ext_vector_type(4)));

__global__ __launch_bounds__(256) void st_lds_kernel(
    const float* __restrict__ input,   // [B,C,H,W]
    const float* __restrict__ theta,   // [B,6]
    float* __restrict__ out)           // [B,C,H,W]
{
    __shared__ float S[SROWS * SCOLS];

    // Chunked XCD swizzle (2048 % 8 == 0, bijective): each XCD gets 4
    // consecutive images worth of tiles -> row-band reuse stays in its L2.
    int bid = blockIdx.x;
    int wg = (bid & (NXCD - 1)) * (NBLK / NXCD) + (bid >> 3);

    int b  = wg >> 6;              // 64 tiles per image
    int r  = wg & 63;
    int yt = r >> 2;
    int xt = r & 3;

    int tid = threadIdx.x;
    int qy = tid >> 4;             // 0..15: row within tile
    int qx = tid & 15;             // 0..15: col-quad within tile
    int oy  = yt * TH + qy;
    int oxb = xt * TW + qx * 4;    // 4 consecutive x-pixels per thread

    const float* th = theta + b * 6;
    float t0 = th[0], t1 = th[1], t2 = th[2];
    float t3 = th[3], t4 = th[4], t5 = th[5];

    const float step = 2.0f / 255.0f;

    // ---- staging window from tile-corner bounds (affine => corners bound all) ----
    float gxa = -1.0f + (xt * TW) * step;
    float gxb = -1.0f + (xt * TW + TW - 1) * step;
    float gya = -1.0f + (yt * TH) * step;
    float gyb = -1.0f + (yt * TH + TH - 1) * step;

    float x00 = t0 * gxa + t1 * gya + t2, x01 = t0 * gxa + t1 * gyb + t2;
    float x10 = t0 * gxb + t1 * gya + t2, x11 = t0 * gxb + t1 * gyb + t2;
    float y00 = t3 * gxa + t4 * gya + t5, y01 = t3 * gxa + t4 * gyb + t5;
    float y10 = t3 * gxb + t4 * gya + t5, y11 = t3 * gxb + t4 * gyb + t5;

    float xmn = fminf(fminf(x00, x01), fminf(x10, x11));
    float xmx = fmaxf(fmaxf(x00, x01), fmaxf(x10, x11));
    float ymn = fminf(fminf(y00, y01), fminf(y10, y11));
    float ymx = fmaxf(fmaxf(y00, y01), fmaxf(y10, y11));
    // clip is monotone: bounds of clipped values = clipped bounds
    xmn = fminf(fmaxf(xmn, -1.0f), 1.0f) ;
    xmx = fminf(fmaxf(xmx, -1.0f), 1.0f);
    ymn = fminf(fmaxf(ymn, -1.0f), 1.0f);
    ymx = fminf(fmaxf(ymx, -1.0f), 1.0f);
    float pxmn = (xmn + 1.0f) * 127.5f, pxmx = (xmx + 1.0f) * 127.5f;
    float pymn = (ymn + 1.0f) * 127.5f, pymx = (ymx + 1.0f) * 127.5f;

    int cx0 = (int)floorf(pxmn) - 2;
    cx0 = max(0, min(cx0, WW - SCOLS)) & ~3;        // 16B-aligned window start
    int ry0 = (int)floorf(pymn) - 2;
    ry0 = max(0, min(ry0, HH - 1));
    int ryend = min((int)floorf(pymx) + 3, HH - 1); // inclusive
    int rows = min(min(ryend - ry0 + 1, SROWS), HH - ry0);
    int nf4 = rows * SF4;

    // ---- per-pixel offsets & weights (constant across channels) ----
    int   off[4], goff[4];
    float w00[4], w01[4], w10[4], w11[4];
    bool  ok[4];
    float gy = -1.0f + oy * step;
    float cxp = t1 * gy + t2;
    float cyp = t4 * gy + t5;

    #pragma unroll
    for (int j = 0; j < 4; ++j) {
        float gx = -1.0f + (oxb + j) * step;
        float xs = fminf(fmaxf(t0 * gx + cxp, -1.0f), 1.0f);
        float ys = fminf(fmaxf(t3 * gx + cyp, -1.0f), 1.0f);
        float x = (xs + 1.0f) * 127.5f;
        float y = (ys + 1.0f) * 127.5f;
        // bx = min(floor(x),254), fx = x-bx in [0,1] reproduces the
        // reference's index-clamp semantics exactly (R3-verified).
        float bxf = fminf(floorf(x), 254.0f);
        float byf = fminf(floorf(y), 254.0f);
        float fx = x - bxf, fy = y - byf;
        int bx = (int)bxf, by = (int)byf;

        w00[j] = (1.0f - fx) * (1.0f - fy);
        w01[j] = fx * (1.0f - fy);
        w10[j] = (1.0f - fx) * fy;
        w11[j] = fx * fy;

        int lx = bx - cx0, ly = by - ry0;
        ok[j] = (lx >= 0) && (lx <= SCOLS - 2) && (ly >= 0) && (ly <= rows - 2);
        off[j]  = ly * SCOLS + lx;
        goff[j] = by * WW + bx;
    }

    const float* ibase = input + (size_t)b * CC * HWSZ;
    float* obase = out + (size_t)b * CC * HWSZ + (size_t)oy * WW + oxb;

    for (int c = 0; c < CC; ++c) {
        __syncthreads();                      // previous compute done with S
        // ---- stage band [ry0, ry0+rows) x [cx0, cx0+SCOLS) densely ----
        const float* src = ibase + c * HWSZ + ry0 * WW + cx0;
        for (int idx = tid; idx < nf4; idx += 256) {
            int rr = (idx * 2731) >> 16;      // idx / 24  (idx < 1344)
            int cq = idx - rr * SF4;
            f4 v = *(const f4*)(src + rr * WW + cq * 4);   // 16B-aligned
            *(f4*)&S[rr * SCOLS + cq * 4] = v;
        }
        __syncthreads();

        const float* p = ibase + c * HWSZ;
        f4 ov;
        #pragma unroll
        for (int j = 0; j < 4; ++j) {
            float v00, v01, v10, v11;
            if (ok[j]) {
                v00 = S[off[j]];
                v01 = S[off[j] + 1];
                v10 = S[off[j] + SCOLS];
                v11 = S[off[j] + SCOLS + 1];
            } else {
                // exact fallback path (rare: window capacity exceeded)
                f2 a, bb;
                __builtin_memcpy(&a,  p + goff[j], 8);
                __builtin_memcpy(&bb, p + goff[j] + WW, 8);
                v00 = a.x; v01 = a.y; v10 = bb.x; v11 = bb.y;
            }
            ov[j] = v00 * w00[j] + v01 * w01[j] + v10 * w10[j] + v11 * w11[j];
        }
        __builtin_nontemporal_store(ov, (f4*)(obase + c * HWSZ));
    }
}

extern "C" void kernel_launch(void* const* d_in, const int* in_sizes, int n_in,
                              void* d_out, int out_size, void* d_ws, size_t ws_size,
                              hipStream_t stream) {
    const float* input = (const float*)d_in[0];
    const float* theta = (const float*)d_in[1];
    float* out = (float*)d_out;

    dim3 block(256);
    dim3 grid(NBLK);   // 2048 blocks
    hipLaunchKernelGGL(st_lds_kernel, grid, block, 0, stream,
                       input, theta, out);
}

// Round 5
// 55.128 us; speedup vs baseline: 1.0395x; 1.0395x over previous
//
#include <hip/hip_runtime.h>

#define BB 32
#define CC 16
#define HH 256
#define WW 256
#define HWSZ (HH * WW)

#define TW 64                  // tile width (x)
#define TH 16                  // tile height (y)
#define NBLK (BB * (WW/TW) * (HH/TH))   // 2048 blocks
#define NXCD 8

#define SROWS 48               // staged row capacity
#define SCOLS 100              // LDS row stride: 100 % 32 == 4 -> conflict-free phase shift
#define MAXF4 25               // 100 floats = 25 f4 per row max
#define KMAX 5                 // ceil(SROWS*MAXF4 / 256) = ceil(1200/256)

typedef float f2 __attribute__((ext_vector_type(2)));
typedef float f4 __attribute__((ext_vector_type(4)));

__global__ __launch_bounds__(256) void st_lds2_kernel(
    const float* __restrict__ input,   // [B,C,H,W]
    const float* __restrict__ theta,   // [B,6]
    float* __restrict__ out)           // [B,C,H,W]
{
    __shared__ float S[SROWS * SCOLS];   // 19.2 KB -> 8 blocks/CU

    // Chunked XCD swizzle (2048 % 8 == 0, bijective)
    int bid = blockIdx.x;
    int wg = (bid & (NXCD - 1)) * (NBLK / NXCD) + (bid >> 3);

    int b  = wg >> 6;              // 64 tiles per image
    int r  = wg & 63;
    int yt = r >> 2;               // 16 y-tiles
    int xt = r & 3;                // 4 x-tiles

    int tid = threadIdx.x;
    int qy = tid >> 4;             // 0..15
    int qx = tid & 15;             // 0..15
    int oy  = yt * TH + qy;
    int oxb = xt * TW + qx * 4;

    const float* th = theta + b * 6;
    float t0 = th[0], t1 = th[1], t2 = th[2];
    float t3 = th[3], t4 = th[4], t5 = th[5];

    const float step = 2.0f / 255.0f;

    // ---- staging window from tile-corner bounds (affine + monotone clip) ----
    float gxa = -1.0f + (xt * TW) * step;
    float gxb = -1.0f + (xt * TW + TW - 1) * step;
    float gya = -1.0f + (yt * TH) * step;
    float gyb = -1.0f + (yt * TH + TH - 1) * step;

    float x00 = t0 * gxa + t1 * gya + t2, x01 = t0 * gxa + t1 * gyb + t2;
    float x10 = t0 * gxb + t1 * gya + t2, x11 = t0 * gxb + t1 * gyb + t2;
    float y00 = t3 * gxa + t4 * gya + t5, y01 = t3 * gxa + t4 * gyb + t5;
    float y10 = t3 * gxb + t4 * gya + t5, y11 = t3 * gxb + t4 * gyb + t5;

    float xmn = fminf(fminf(x00, x01), fminf(x10, x11));
    float xmx = fmaxf(fmaxf(x00, x01), fmaxf(x10, x11));
    float ymn = fminf(fminf(y00, y01), fminf(y10, y11));
    float ymx = fmaxf(fmaxf(y00, y01), fmaxf(y10, y11));
    xmn = fminf(fmaxf(xmn, -1.0f), 1.0f);
    xmx = fminf(fmaxf(xmx, -1.0f), 1.0f);
    ymn = fminf(fmaxf(ymn, -1.0f), 1.0f);
    ymx = fminf(fmaxf(ymx, -1.0f), 1.0f);
    float pxmn = (xmn + 1.0f) * 127.5f, pxmx = (xmx + 1.0f) * 127.5f;
    float pymn = (ymn + 1.0f) * 127.5f, pymx = (ymx + 1.0f) * 127.5f;

    int cx0 = (int)floorf(pxmn) - 2;
    cx0 = (max(0, min(cx0, WW - 4))) & ~3;              // 16B-aligned start
    int cxend = min((int)floorf(pxmx) + 3, WW - 1);     // inclusive last col needed
    int wf4 = (cxend - cx0 + 4) >> 2;                   // ceil((cxend-cx0+1)/4)
    wf4 = min(wf4, min(MAXF4, (WW - cx0) >> 2));        // capacity + image-edge cap
    int wcols = wf4 * 4;

    int ry0 = (int)floorf(pymn) - 2;
    ry0 = max(0, min(ry0, HH - 1));
    int ryend = min((int)floorf(pymx) + 3, HH - 1);
    int rows = min(min(ryend - ry0 + 1, SROWS), HH - ry0);
    int nf4 = rows * wf4;

    // ---- precompute stage slots ONCE (channel-invariant) ----
    int  sg[KMAX], sl[KMAX];
    bool sv[KMAX];
    #pragma unroll
    for (int k = 0; k < KMAX; ++k) {
        int idx = tid + k * 256;
        sv[k] = idx < nf4;
        int rr = idx / wf4;            // wf4 >= 1 always
        int cq = idx - rr * wf4;
        sg[k] = rr * WW + cq * 4;      // global float offset within window
        sl[k] = rr * SCOLS + cq * 4;   // LDS float offset
    }

    // ---- per-pixel offsets & weights (channel-invariant) ----
    int   off[4], goff[4];
    float w00[4], w01[4], w10[4], w11[4];
    bool  ok[4];
    float gy = -1.0f + oy * step;
    float cxp = t1 * gy + t2;
    float cyp = t4 * gy + t5;

    #pragma unroll
    for (int j = 0; j < 4; ++j) {
        float gx = -1.0f + (oxb + j) * step;
        float xs = fminf(fmaxf(t0 * gx + cxp, -1.0f), 1.0f);
        float ys = fminf(fmaxf(t3 * gx + cyp, -1.0f), 1.0f);
        float x = (xs + 1.0f) * 127.5f;
        float y = (ys + 1.0f) * 127.5f;
        // bx=min(floor(x),254), fx=x-bx in [0,1]: exact index-clamp semantics
        float bxf = fminf(floorf(x), 254.0f);
        float byf = fminf(floorf(y), 254.0f);
        float fx = x - bxf, fy = y - byf;
        int bx = (int)bxf, by = (int)byf;

        w00[j] = (1.0f - fx) * (1.0f - fy);
        w01[j] = fx * (1.0f - fy);
        w10[j] = (1.0f - fx) * fy;
        w11[j] = fx * fy;

        int lx = bx - cx0, ly = by - ry0;
        ok[j] = (lx >= 0) && (lx <= wcols - 2) && (ly >= 0) && (ly <= rows - 2);
        off[j]  = ly * SCOLS + lx;
        goff[j] = by * WW + bx;
    }

    const float* ibase = input + (size_t)b * CC * HWSZ;
    float* obase = out + (size_t)b * CC * HWSZ + (size_t)oy * WW + oxb;

    for (int c = 0; c < CC; ++c) {
        __syncthreads();               // previous iteration done reading S
        const float* src = ibase + c * HWSZ + ry0 * WW + cx0;
        #pragma unroll
        for (int k = 0; k < KMAX; ++k) {
            if (sv[k]) {
                *(f4*)&S[sl[k]] = *(const f4*)(src + sg[k]);
            }
        }
        __syncthreads();

        const float* p = ibase + c * HWSZ;
        f4 ov;
        #pragma unroll
        for (int j = 0; j < 4; ++j) {
            float v00, v01, v10, v11;
            if (ok[j]) {
                // adjacent-dword pairs -> ds_read2_b32 x2
                v00 = S[off[j]];
                v01 = S[off[j] + 1];
                v10 = S[off[j] + SCOLS];
                v11 = S[off[j] + SCOLS + 1];
            } else {
                f2 a, bb;   // exact global fallback (rare)
                __builtin_memcpy(&a,  p + goff[j], 8);
                __builtin_memcpy(&bb, p + goff[j] + WW, 8);
                v00 = a.x; v01 = a.y; v10 = bb.x; v11 = bb.y;
            }
            ov[j] = v00 * w00[j] + v01 * w01[j] + v10 * w10[j] + v11 * w11[j];
        }
        __builtin_nontemporal_store(ov, (f4*)(obase + c * HWSZ));
    }
}

extern "C" void kernel_launch(void* const* d_in, const int* in_sizes, int n_in,
                              void* d_out, int out_size, void* d_ws, size_t ws_size,
                              hipStream_t stream) {
    const float* input = (const float*)d_in[0];
    const float* theta = (const float*)d_in[1];
    float* out = (float*)d_out;

    dim3 block(256);
    dim3 grid(NBLK);   // 2048 blocks
    hipLaunchKernelGGL(st_lds2_kernel, grid, block, 0, stream,
                       input, theta, out);
}